// Round 5
// baseline (1760.199 us; speedup 1.0000x reference)
//
#include <hip/hip_runtime.h>
#include <hip/hip_bf16.h>
#include <cstdint>

// Problem constants
#define B_   1024
#define V_   16
#define NH_  32
#define SH_  8
#define D_   128
#define KV_  1024
#define H_   4096

typedef __bf16 bf16;
typedef bf16  bf16x8 __attribute__((ext_vector_type(8)));
typedef float f32x2  __attribute__((ext_vector_type(2)));
typedef float f32x4  __attribute__((ext_vector_type(4)));

#define VMCNT(n) asm volatile("s_waitcnt vmcnt(" #n ")" ::: "memory")
#define LGKM0()  asm volatile("s_waitcnt lgkmcnt(0)" ::: "memory")

// async global->LDS, 16B per lane. LDS dest is wave-uniform base + lane*16.
__device__ __forceinline__ void gl2lds16(const void* g, void* l) {
    __builtin_amdgcn_global_load_lds((const __attribute__((address_space(1))) void*)g,
                                     (__attribute__((address_space(3))) void*)l,
                                     16, 0, 0);
}

// ---------------------------------------------------------------------------
// K1: h1[v][b][k] = tanh(prefix[b][v] * W1[v][k] + b1[v][k])  (bf16 out)
// ---------------------------------------------------------------------------
__global__ __launch_bounds__(256)
void h1_kernel(const float* __restrict__ prefix, const float* __restrict__ W1,
               const float* __restrict__ b1, bf16* __restrict__ h1)
{
    int gid = blockIdx.x * 256 + threadIdx.x;   // V_*B_*KV_/8 = 2M threads
    int k8  = gid & 127;                        // KV_/8 = 128
    int b   = (gid >> 7) & 1023;
    int v   = gid >> 17;
    float x = prefix[b * V_ + v];
    const float* wp = W1 + (size_t)v * KV_ + k8 * 8;
    const float* bp = b1 + (size_t)v * KV_ + k8 * 8;
    f32x4 w0 = *(const f32x4*)wp,       w1 = *(const f32x4*)(wp + 4);
    f32x4 q0 = *(const f32x4*)bp,       q1 = *(const f32x4*)(bp + 4);
    bf16x8 o;
#pragma unroll
    for (int j = 0; j < 4; ++j) o[j]     = (bf16)tanhf(fmaf(x, w0[j], q0[j]));
#pragma unroll
    for (int j = 0; j < 4; ++j) o[4 + j] = (bf16)tanhf(fmaf(x, w1[j], q1[j]));
    *(bf16x8*)(h1 + (size_t)gid * 8) = o;
}

// ---------------------------------------------------------------------------
// K2: pipelined GEMM, fused B-transpose+fp32->bf16, counted-vmcnt schedule.
//   C[v] = A[v] (M=1024 x KDIM, bf16 row-major) * Bf[v] ([KDIM][NDIM] fp32)
// MODE 0: out = tanh(C + bias) -> bf16 [V][M][NDIM]   (h2)
// MODE 1: out = C + bias -> fp32 scattered to [B,NH,V,D], 4-way head rep,
//         via per-wave LDS transpose so every store is 256B contiguous.
//
// 128x128 tile, BK=64, 4 waves (2x2), 4x4 16x16x32 MFMA frags per wave.
// Pipeline (T3/T4): A triple-buffered LDS via gl2lds issued 2 tiles ahead;
// B reg-staged in 2 banks issued 2 tiles ahead. Per step:
//   issue A(kt+2), br(kt+2) | MFMA(kt) | vmcnt(20) (retires A/br(kt+1),
//   keeps 20 in flight) | cvt+ds_write B(kt+1) | lgkmcnt(0) | raw s_barrier.
// No vmcnt(0) in steady state -> every load gets a full iteration in flight.
// ---------------------------------------------------------------------------
template<int MODE, int KDIM, int NDIM>
__global__ __launch_bounds__(256)
void gemm_pipe(const bf16* __restrict__ A, const float* __restrict__ Bf,
               const float* __restrict__ bias,
               bf16* __restrict__ outB, float* __restrict__ outF)
{
    // aBuf: 3 x 16KB at [0, 49152); bBuf: 2 x 16KB at [49152, 81920)
    __shared__ __align__(16) char smem[81920];

    const int v  = blockIdx.z;
    const int m0 = blockIdx.y * 128;
    const int n0 = blockIdx.x * 128;
    const int t  = threadIdx.x;
    const int l  = t & 63;
    const int w  = t >> 6;          // wave id; also the k-quarter for B staging
    const int wm = (w >> 1) * 64;
    const int wn = (w & 1) * 64;
    constexpr int NT = KDIM / 64;

    const bf16*  Av = A  + (size_t)v * 1024 * KDIM + (size_t)m0 * KDIM;
    const float* Bv = Bf + (size_t)v * KDIM * NDIM + n0;

    f32x4 acc[4][4];
#pragma unroll
    for (int i = 0; i < 4; ++i)
#pragma unroll
        for (int j = 0; j < 4; ++j) acc[i][j] = f32x4{0.f, 0.f, 0.f, 0.f};

    // B staging: wave w covers k-rows [w*16, w*16+16), lane l covers n=2l,2l+1
    const float* bptr = Bv + (size_t)(w * 16) * NDIM + 2 * l;
    f32x2 brA[16], brB[16];

    // helper: issue the 4 gl2lds for A(kt) into aBuf[ab]
    auto stageA = [&](int ktile, int ab) {
#pragma unroll
        for (int i = 0; i < 4; ++i) {
            const int off = t + i * 256;
            const int row = off >> 3;
            const int gc  = (off & 7) ^ ((row >> 1) & 7);
            gl2lds16(Av + (size_t)row * KDIM + ktile * 64 + gc * 8,
                     smem + (size_t)ab * 16384 + (size_t)(w * 64 + i * 256) * 16);
        }
    };
    // helper: cvt+transposed swizzled ds_write of bank -> bBuf[bb]
    auto writeB = [&](f32x2 (&bank)[16], int bb) {
        bf16* bN = (bf16*)(smem + 49152 + (size_t)bb * 16384);
#pragma unroll
        for (int i = 0; i < 2; ++i)
#pragma unroll
            for (int h = 0; h < 2; ++h) {
                bf16x8 pk;
#pragma unroll
                for (int jj = 0; jj < 8; ++jj) pk[jj] = (bf16)bank[h * 8 + jj][i];
                const int n  = 2 * l + i;
                const int ch = (w * 2 + h) ^ (l & 7);
                *(bf16x8*)(bN + n * 64 + ch * 8) = pk;
            }
    };

    // ---- prologue: A(0)[4], br(0)[16], A(1)[4]; retire first 20; B(0); br(1)
    stageA(0, 0);
#pragma unroll
    for (int j = 0; j < 16; ++j) brA[j] = *(const f32x2*)(bptr + (size_t)j * NDIM);
    stageA(1, 1);
    VMCNT(4);                       // A(0)+br(0) done; A(1) still in flight
    writeB(brA, 0);
#pragma unroll
    for (int j = 0; j < 16; ++j)
        brB[j] = *(const f32x2*)(bptr + (size_t)64 * NDIM + (size_t)j * NDIM);
    LGKM0();
    __builtin_amdgcn_s_barrier();   // outstanding: A(1)[4] + br(1)[16] = 20

    // ---- steady loop, 2 steps per iteration (static br bank selection) ----
    auto step = [&](int kt, f32x2 (&brIss)[16], f32x2 (&brUse)[16]) {
        const bool haveN2 = (kt + 2 < NT);
        if (haveN2) {
            stageA(kt + 2, (kt + 2) % 3);
            const float* np = bptr + (size_t)(kt + 2) * 64 * NDIM;
#pragma unroll
            for (int j = 0; j < 16; ++j)
                brIss[j] = *(const f32x2*)(np + (size_t)j * NDIM);
        }
        __builtin_amdgcn_sched_barrier(0);

        // MFMA phase on aBuf[kt%3], bBuf[kt&1]
        const bf16* aC = (const bf16*)(smem + (size_t)(kt % 3) * 16384);
        const bf16* bC = (const bf16*)(smem + 49152 + (size_t)(kt & 1) * 16384);
#pragma unroll
        for (int kk = 0; kk < 2; ++kk) {
            bf16x8 af[4], bfv[4];
#pragma unroll
            for (int f = 0; f < 4; ++f) {
                const int mr = wm + f * 16 + (l & 15);
                const int ca = (kk * 4 + (l >> 4)) ^ ((mr >> 1) & 7);
                af[f]  = *(const bf16x8*)(aC + mr * 64 + ca * 8);
                const int nr = wn + f * 16 + (l & 15);
                const int cb = (kk * 4 + (l >> 4)) ^ ((nr >> 1) & 7);
                bfv[f] = *(const bf16x8*)(bC + nr * 64 + cb * 8);
            }
#pragma unroll
            for (int fm = 0; fm < 4; ++fm)
#pragma unroll
                for (int fn = 0; fn < 4; ++fn)
                    acc[fm][fn] = __builtin_amdgcn_mfma_f32_16x16x32_bf16(
                        af[fm], bfv[fn], acc[fm][fn], 0, 0, 0);
        }
        __builtin_amdgcn_sched_barrier(0);

        if (kt + 1 < NT) {
            if (haveN2) { VMCNT(20); }   // retire A(kt+1)+br(kt+1), keep 20
            else        { VMCNT(0);  }   // tail: nothing younger to keep
            writeB(brUse, (kt + 1) & 1);
            LGKM0();
            __builtin_amdgcn_s_barrier();
        }
    };
    for (int kt = 0; kt < NT; kt += 2) {
        step(kt,     brA, brB);
        step(kt + 1, brB, brA);
    }

    // ---- epilogue. C/D frag: col = lane&15, row = (lane>>4)*4 + reg ----
    const int rbase = (l >> 4) * 4;
    const int cbase = l & 15;
    if (MODE == 0) {
#pragma unroll
        for (int fn = 0; fn < 4; ++fn) {
            const int nc = n0 + wn + fn * 16 + cbase;
            const float bv = bias[(size_t)v * NDIM + nc];
#pragma unroll
            for (int fm = 0; fm < 4; ++fm)
#pragma unroll
                for (int j = 0; j < 4; ++j) {
                    const int mr = m0 + wm + fm * 16 + rbase + j;
                    outB[(size_t)v * 1024 * NDIM + (size_t)mr * NDIM + nc] =
                        (bf16)tanhf(acc[fm][fn][j] + bv);
                }
        }
    } else {
        __syncthreads();   // LDS buffers may still be read by other waves
        // stage C tile into per-wave LDS scratch (XOR-swizzled, 2-way = free),
        // then read back 4 consecutive cols per lane -> 256B-contiguous stores.
        float* scr = (float*)(smem + (size_t)w * 16384);   // 64x64 f32
#pragma unroll
        for (int fm = 0; fm < 4; ++fm)
#pragma unroll
            for (int fn = 0; fn < 4; ++fn)
#pragma unroll
                for (int j = 0; j < 4; ++j) {
                    const int r = fm * 16 + rbase + j;
                    const int c = fn * 16 + cbase;
                    scr[r * 64 + (c ^ (((r >> 2) & 1) << 4))] = acc[fm][fn][j];
                }
        const int nb = n0 + wn;          // wave col base (multiple of 64)
        const int sh = nb >> 7;          // slider head
        const int db = nb & 127;         // 0 or 64
        const int c4 = (l & 15) * 4;
        f32x4 bv4;
#pragma unroll
        for (int q = 0; q < 4; ++q) bv4[q] = bias[(size_t)v * NDIM + nb + c4 + q];
#pragma unroll
        for (int i = 0; i < 16; ++i) {
            const int r = i * 4 + (l >> 4);
            f32x4 val = *(const f32x4*)&scr[r * 64 + (c4 ^ ((i & 1) << 4))];
#pragma unroll
            for (int q = 0; q < 4; ++q) val[q] += bv4[q];
            const int mr = m0 + wm + r;
            float* p = outF + (size_t)mr * (NH_ * V_ * D_)
                            + (size_t)(sh * 4) * (V_ * D_)
                            + (size_t)v * D_ + db + c4;
            *(f32x4*)(p)               = val;
            *(f32x4*)(p + V_ * D_)     = val;
            *(f32x4*)(p + 2 * V_ * D_) = val;
            *(f32x4*)(p + 3 * V_ * D_) = val;
        }
    }
}

// ---------------------------------------------------------------------------
__global__ void tail_kernel(const float* __restrict__ af, float* __restrict__ out)
{
    out[0] = af[0];
}

// ---------------------------------------------------------------------------
extern "C" void kernel_launch(void* const* d_in, const int* in_sizes, int n_in,
                              void* d_out, int out_size, void* d_ws, size_t ws_size,
                              hipStream_t stream)
{
    const float* prefix = (const float*)d_in[0];
    const float* W1[2]  = {(const float*)d_in[1], (const float*)d_in[7]};
    const float* b1[2]  = {(const float*)d_in[2], (const float*)d_in[8]};
    const float* W2[2]  = {(const float*)d_in[3], (const float*)d_in[9]};
    const float* b2[2]  = {(const float*)d_in[4], (const float*)d_in[10]};
    const float* W3[2]  = {(const float*)d_in[5], (const float*)d_in[11]};
    const float* b3[2]  = {(const float*)d_in[6], (const float*)d_in[12]};
    const float* afac   = (const float*)d_in[13];

    // workspace: h1 = V*B*KV bf16 (32 MiB), h2 = V*B*H bf16 (128 MiB)
    bf16* h1 = (bf16*)d_ws;
    bf16* h2 = (bf16*)((char*)d_ws + (size_t)33554432);
    float* outp = (float*)d_out;

    for (int m = 0; m < 2; ++m) {
        // h1 = tanh(x*W1 + b1)
        h1_kernel<<<8192, 256, 0, stream>>>(prefix, W1[m], b1[m], h1);
        // h2 = tanh(h1 @ W2 + b2)   (B-transpose fused into staging)
        gemm_pipe<0, 1024, 4096><<<dim3(32, 8, 16), 256, 0, stream>>>(
            h1, W2[m], b2[m], h2, nullptr);
        // out = h2 @ W3 + b3, scattered into keys (m=0) / values (m=1)
        gemm_pipe<1, 4096, 1024><<<dim3(8, 8, 16), 256, 0, stream>>>(
            h2, W3[m], b3[m], nullptr, outp + (size_t)m * (B_ * NH_ * V_ * D_));
    }
    tail_kernel<<<1, 1, 0, stream>>>(afac, outp + (size_t)2 * B_ * NH_ * V_ * D_);
}

// Round 6
// 1259.634 us; speedup vs baseline: 1.3974x; 1.3974x over previous
//
#include <hip/hip_runtime.h>
#include <hip/hip_bf16.h>
#include <cstdint>

// Problem constants
#define B_   1024
#define V_   16
#define NH_  32
#define SH_  8
#define D_   128
#define KV_  1024
#define H_   4096

typedef __bf16 bf16;
typedef bf16  bf16x8 __attribute__((ext_vector_type(8)));
typedef float f32x2  __attribute__((ext_vector_type(2)));
typedef float f32x4  __attribute__((ext_vector_type(4)));

#define VMCNT(n) asm volatile("s_waitcnt vmcnt(" #n ")" ::: "memory")
#define LGKM0()  asm volatile("s_waitcnt lgkmcnt(0)" ::: "memory")

// async global->LDS, 16B per lane. LDS dest is wave-uniform base + lane*16.
__device__ __forceinline__ void gl2lds16(const void* g, void* l) {
    __builtin_amdgcn_global_load_lds((const __attribute__((address_space(1))) void*)g,
                                     (__attribute__((address_space(3))) void*)l,
                                     16, 0, 0);
}

// ---------------------------------------------------------------------------
// K1: h1[v][b][k] = tanh(prefix[b][v] * W1[v][k] + b1[v][k])  (bf16 out)
// ---------------------------------------------------------------------------
__global__ __launch_bounds__(256)
void h1_kernel(const float* __restrict__ prefix, const float* __restrict__ W1,
               const float* __restrict__ b1, bf16* __restrict__ h1)
{
    int gid = blockIdx.x * 256 + threadIdx.x;   // V_*B_*KV_/8 = 2M threads
    int k8  = gid & 127;                        // KV_/8 = 128
    int b   = (gid >> 7) & 1023;
    int v   = gid >> 17;
    float x = prefix[b * V_ + v];
    const float* wp = W1 + (size_t)v * KV_ + k8 * 8;
    const float* bp = b1 + (size_t)v * KV_ + k8 * 8;
    f32x4 w0 = *(const f32x4*)wp,       w1 = *(const f32x4*)(wp + 4);
    f32x4 q0 = *(const f32x4*)bp,       q1 = *(const f32x4*)(bp + 4);
    bf16x8 o;
#pragma unroll
    for (int j = 0; j < 4; ++j) o[j]     = (bf16)tanhf(fmaf(x, w0[j], q0[j]));
#pragma unroll
    for (int j = 0; j < 4; ++j) o[4 + j] = (bf16)tanhf(fmaf(x, w1[j], q1[j]));
    *(bf16x8*)(h1 + (size_t)gid * 8) = o;
}

// ---------------------------------------------------------------------------
// K2: pipelined GEMM, fused B-transpose+fp32->bf16, counted-vmcnt schedule.
//   C[v] = A[v] (M=1024 x KDIM, bf16 row-major) * Bf[v] ([KDIM][NDIM] fp32)
// MODE 0: out = tanh(C + bias) -> bf16 [V][M][NDIM]   (h2)
// MODE 1: out = C + bias -> fp32 scattered to [B,NH,V,D], 4-way head rep,
//         via per-wave LDS transpose so every store is 256B contiguous.
//
// 128x128 tile, BK=64, 4 waves (2x2), 4x4 16x16x32 MFMA frags per wave.
// 64KB LDS (A dbuf 2x16K, B dbuf 2x16K) -> 2 blocks/CU (R5's 80KB broke this).
// Pipeline: A gl2lds 1 step ahead; br (B regs) 2 steps ahead in 2 banks.
// Steady step kt:
//   stageA(kt+1) | issue br(kt+2) | MFMA(kt) | VMCNT(20) retire br(kt+1)
//   | writeB(kt+1) | VMCNT(16) retire A(kt+1), keep br(kt+2) flying
//   | LGKM0 | raw s_barrier.
// No vmcnt(0) in steady state; br gets ~1.5 steps in flight, A ~1 step.
// ---------------------------------------------------------------------------
template<int MODE, int KDIM, int NDIM>
__global__ __launch_bounds__(256)
void gemm_p2(const bf16* __restrict__ A, const float* __restrict__ Bf,
             const float* __restrict__ bias,
             bf16* __restrict__ outB, float* __restrict__ outF)
{
    // aBuf: 2 x 16KB at [0, 32768); bBuf: 2 x 16KB at [32768, 65536)
    __shared__ __align__(16) char smem[65536];

    const int v  = blockIdx.z;
    const int m0 = blockIdx.y * 128;
    const int n0 = blockIdx.x * 128;
    const int t  = threadIdx.x;
    const int l  = t & 63;
    const int w  = t >> 6;          // wave id; also the k-quarter for B staging
    const int wm = (w >> 1) * 64;
    const int wn = (w & 1) * 64;
    constexpr int NT = KDIM / 64;
    static_assert(NT >= 4 && (NT % 2) == 0, "NT must be even and >= 4");

    const bf16*  Av = A  + (size_t)v * 1024 * KDIM + (size_t)m0 * KDIM;
    const float* Bv = Bf + (size_t)v * KDIM * NDIM + n0;

    f32x4 acc[4][4];
#pragma unroll
    for (int i = 0; i < 4; ++i)
#pragma unroll
        for (int j = 0; j < 4; ++j) acc[i][j] = f32x4{0.f, 0.f, 0.f, 0.f};

    // B staging: wave w covers k-rows [w*16, w*16+16), lane l covers n=2l,2l+1
    const float* bptr = Bv + (size_t)(w * 16) * NDIM + 2 * l;
    f32x2 brA[16], brB[16];

    auto loadBR = [&](int ktile, f32x2 (&bank)[16]) {
        const float* np = bptr + (size_t)ktile * 64 * NDIM;
#pragma unroll
        for (int j = 0; j < 16; ++j) bank[j] = *(const f32x2*)(np + (size_t)j * NDIM);
    };
    auto stageA = [&](int ktile, int ab) {
#pragma unroll
        for (int i = 0; i < 4; ++i) {
            const int off = t + i * 256;
            const int row = off >> 3;
            const int gc  = (off & 7) ^ ((row >> 1) & 7);
            gl2lds16(Av + (size_t)row * KDIM + ktile * 64 + gc * 8,
                     smem + (size_t)ab * 16384 + (size_t)(w * 64 + i * 256) * 16);
        }
    };
    auto writeB = [&](f32x2 (&bank)[16], int bb) {
        bf16* bN = (bf16*)(smem + 32768 + (size_t)bb * 16384);
#pragma unroll
        for (int i = 0; i < 2; ++i)
#pragma unroll
            for (int h = 0; h < 2; ++h) {
                bf16x8 pk;
#pragma unroll
                for (int jj = 0; jj < 8; ++jj) pk[jj] = (bf16)bank[h * 8 + jj][i];
                const int n  = 2 * l + i;
                const int ch = (w * 2 + h) ^ (l & 7);
                *(bf16x8*)(bN + n * 64 + ch * 8) = pk;
            }
    };
    auto mfmaStep = [&](int kt) {
        const bf16* aC = (const bf16*)(smem + (size_t)(kt & 1) * 16384);
        const bf16* bC = (const bf16*)(smem + 32768 + (size_t)(kt & 1) * 16384);
#pragma unroll
        for (int kk = 0; kk < 2; ++kk) {
            bf16x8 af[4], bfv[4];
#pragma unroll
            for (int f = 0; f < 4; ++f) {
                const int mr = wm + f * 16 + (l & 15);
                const int ca = (kk * 4 + (l >> 4)) ^ ((mr >> 1) & 7);
                af[f]  = *(const bf16x8*)(aC + mr * 64 + ca * 8);
                const int nr = wn + f * 16 + (l & 15);
                const int cb = (kk * 4 + (l >> 4)) ^ ((nr >> 1) & 7);
                bfv[f] = *(const bf16x8*)(bC + nr * 64 + cb * 8);
            }
#pragma unroll
            for (int fm = 0; fm < 4; ++fm)
#pragma unroll
                for (int fn = 0; fn < 4; ++fn)
                    acc[fm][fn] = __builtin_amdgcn_mfma_f32_16x16x32_bf16(
                        af[fm], bfv[fn], acc[fm][fn], 0, 0, 0);
        }
    };

    // ---- prologue: establish invariant "entry of step kt: br(kt+1) in flight"
    stageA(0, 0);                 // A(0)  [4]
    loadBR(0, brA);               // br(0) [16]
    loadBR(1, brB);               // br(1) [16]   outstanding: 36
    VMCNT(16);                    // retire A(0)+br(0); br(1) keeps flying
    writeB(brA, 0);
    LGKM0();
    __builtin_amdgcn_s_barrier(); // tile 0 published; outstanding: br(1)[16]

    // ---- steady loop, unrolled by 2 for static br bank selection ----
    auto stepS = [&](int kt, f32x2 (&brIss)[16], f32x2 (&brUse)[16]) {
        stageA(kt + 1, (kt + 1) & 1);   // A(kt+1) [4]
        loadBR(kt + 2, brIss);          // br(kt+2) [16]; outstanding 36
        mfmaStep(kt);                   // loads fly under MFMA
        VMCNT(20);                      // retire br(kt+1)
        writeB(brUse, (kt + 1) & 1);
        VMCNT(16);                      // retire A(kt+1); br(kt+2) stays out
        LGKM0();
        __builtin_amdgcn_s_barrier();
    };
    for (int kt = 0; kt + 3 < NT; kt += 2) {
        stepS(kt,     brA, brB);
        stepS(kt + 1, brB, brA);
    }
    {   // penultimate step kt = NT-2: entry outstanding br(NT-1) in brB
        stageA(NT - 1, (NT - 1) & 1);
        mfmaStep(NT - 2);
        VMCNT(4);                       // retire br(NT-1)
        writeB(brB, (NT - 1) & 1);
        VMCNT(0);                       // retire A(NT-1)
        LGKM0();
        __builtin_amdgcn_s_barrier();
    }
    mfmaStep(NT - 1);                   // last step: compute only

    // ---- epilogue. C/D frag: col = lane&15, row = (lane>>4)*4 + reg ----
    const int rbase = (l >> 4) * 4;
    const int cbase = l & 15;
    if (MODE == 0) {
#pragma unroll
        for (int fn = 0; fn < 4; ++fn) {
            const int nc = n0 + wn + fn * 16 + cbase;
            const float bv = bias[(size_t)v * NDIM + nc];
#pragma unroll
            for (int fm = 0; fm < 4; ++fm)
#pragma unroll
                for (int j = 0; j < 4; ++j) {
                    const int mr = m0 + wm + fm * 16 + rbase + j;
                    outB[(size_t)v * 1024 * NDIM + (size_t)mr * NDIM + nc] =
                        (bf16)tanhf(acc[fm][fn][j] + bv);
                }
        }
    } else {
        __syncthreads();   // LDS buffers may still be read by other waves
        // stage C tile into per-wave LDS scratch (XOR-swizzled, 2-way = free),
        // then read back 4 consecutive cols per lane -> 256B-contiguous stores.
        float* scr = (float*)(smem + (size_t)w * 16384);   // 64x64 f32
#pragma unroll
        for (int fm = 0; fm < 4; ++fm)
#pragma unroll
            for (int fn = 0; fn < 4; ++fn)
#pragma unroll
                for (int j = 0; j < 4; ++j) {
                    const int r = fm * 16 + rbase + j;
                    const int c = fn * 16 + cbase;
                    scr[r * 64 + (c ^ (((r >> 2) & 1) << 4))] = acc[fm][fn][j];
                }
        const int nb = n0 + wn;          // wave col base (multiple of 64)
        const int sh = nb >> 7;          // slider head
        const int db = nb & 127;         // 0 or 64
        const int c4 = (l & 15) * 4;
        f32x4 bv4;
#pragma unroll
        for (int q = 0; q < 4; ++q) bv4[q] = bias[(size_t)v * NDIM + nb + c4 + q];
#pragma unroll
        for (int i = 0; i < 16; ++i) {
            const int r = i * 4 + (l >> 4);
            f32x4 val = *(const f32x4*)&scr[r * 64 + (c4 ^ ((i & 1) << 4))];
#pragma unroll
            for (int q = 0; q < 4; ++q) val[q] += bv4[q];
            const int mr = m0 + wm + r;
            float* p = outF + (size_t)mr * (NH_ * V_ * D_)
                            + (size_t)(sh * 4) * (V_ * D_)
                            + (size_t)v * D_ + db + c4;
            *(f32x4*)(p)               = val;
            *(f32x4*)(p + V_ * D_)     = val;
            *(f32x4*)(p + 2 * V_ * D_) = val;
            *(f32x4*)(p + 3 * V_ * D_) = val;
        }
    }
}

// ---------------------------------------------------------------------------
__global__ void tail_kernel(const float* __restrict__ af, float* __restrict__ out)
{
    out[0] = af[0];
}

// ---------------------------------------------------------------------------
extern "C" void kernel_launch(void* const* d_in, const int* in_sizes, int n_in,
                              void* d_out, int out_size, void* d_ws, size_t ws_size,
                              hipStream_t stream)
{
    const float* prefix = (const float*)d_in[0];
    const float* W1[2]  = {(const float*)d_in[1], (const float*)d_in[7]};
    const float* b1[2]  = {(const float*)d_in[2], (const float*)d_in[8]};
    const float* W2[2]  = {(const float*)d_in[3], (const float*)d_in[9]};
    const float* b2[2]  = {(const float*)d_in[4], (const float*)d_in[10]};
    const float* W3[2]  = {(const float*)d_in[5], (const float*)d_in[11]};
    const float* b3[2]  = {(const float*)d_in[6], (const float*)d_in[12]};
    const float* afac   = (const float*)d_in[13];

    // workspace: h1 = V*B*KV bf16 (32 MiB), h2 = V*B*H bf16 (128 MiB)
    bf16* h1 = (bf16*)d_ws;
    bf16* h2 = (bf16*)((char*)d_ws + (size_t)33554432);
    float* outp = (float*)d_out;

    for (int m = 0; m < 2; ++m) {
        // h1 = tanh(x*W1 + b1)
        h1_kernel<<<8192, 256, 0, stream>>>(prefix, W1[m], b1[m], h1);
        // h2 = tanh(h1 @ W2 + b2)   (B-transpose fused into staging)
        gemm_p2<0, 1024, 4096><<<dim3(32, 8, 16), 256, 0, stream>>>(
            h1, W2[m], b2[m], h2, nullptr);
        // out = h2 @ W3 + b3, scattered into keys (m=0) / values (m=1)
        gemm_p2<1, 4096, 1024><<<dim3(8, 8, 16), 256, 0, stream>>>(
            h2, W3[m], b3[m], nullptr, outp + (size_t)m * (B_ * NH_ * V_ * D_));
    }
    tail_kernel<<<1, 1, 0, stream>>>(afac, outp + (size_t)2 * B_ * NH_ * V_ * D_);
}